// Round 18
// baseline (193.461 us; speedup 1.0000x reference)
//
#include <hip/hip_runtime.h>
#include <stdint.h>

#define B_N 131072

typedef float        float4_ __attribute__((ext_vector_type(4)));
typedef short        short8  __attribute__((ext_vector_type(8)));
typedef unsigned int uint4_  __attribute__((ext_vector_type(4)));

__device__ __forceinline__ unsigned short f2bf(float f) {
    unsigned int u = __float_as_uint(f);
    u += 0x7fffu + ((u >> 16) & 1u);
    return (unsigned short)(u >> 16);
}
__device__ __forceinline__ unsigned int pack2bf(float lo, float hi) {
    return (unsigned int)f2bf(lo) | ((unsigned int)f2bf(hi) << 16);
}

// ---------------- prep: pack bf16 weights into ws (byte-identical to R8/R14 passer) ----------------
__global__ void aehr_prep(const float* __restrict__ Wmu, const float* __restrict__ Wk,
                          const float* __restrict__ W1, const float* __restrict__ W2,
                          const float* __restrict__ W3,
                          unsigned short* __restrict__ wct, unsigned short* __restrict__ w1t,
                          unsigned short* __restrict__ w2k, unsigned short* __restrict__ w3p) {
    int idx = blockIdx.x * 256 + threadIdx.x;
    if (idx < 48 * 512) {
        int n = idx >> 9, k = idx & 511;
        float v = 0.0f;
        if (n < 32) v = Wmu[k * 32 + n];
        else if (n == 32) v = Wk[k];
        wct[idx] = f2bf(v);
    } else if (idx < 48 * 512 + 512 * 32) {
        int j = idx - 48 * 512;
        int n = j >> 5, k = j & 31;
        w1t[j] = f2bf(W1[k * 512 + n]);
    } else if (idx < 48 * 512 + 512 * 32 + 512 * 512) {
        int j = idx - (48 * 512 + 512 * 32);
        int i = j & 7, t = j >> 3;
        int n = t & 511, gk = t >> 9;      // gk 0..63
        int g = gk & 3, ks = gk >> 2;
        int col = ks * 32 + ((i < 4) ? (4 * g + i) : (16 + 4 * g + (i - 4)));
        w2k[j] = f2bf(W2[col * 512 + n]);
    } else if (idx < 48 * 512 + 512 * 32 + 512 * 512 + 32 * 512) {
        int j = idx - (48 * 512 + 512 * 32 + 512 * 512);
        int n = j >> 9, slot = j & 511;
        int s = slot >> 5, q = slot & 31, g = (q >> 3) & 3, i = q & 7;
        int col = s * 32 + ((i < 4) ? (4 * g + i) : (16 + 4 * g + (i - 4)));
        w3p[j] = f2bf(W3[col * 32 + n]);
    }
}

// ---------------- front: R14 passer (fast transcendentals), byte-identical ----------------
__global__ __launch_bounds__(256, 4) void aehr_front(
    const float* __restrict__ h, const float* __restrict__ v,
    const float* __restrict__ zu, const float* __restrict__ uu,
    const float* __restrict__ bmu, const float* __restrict__ bk,
    const unsigned short* __restrict__ wct,
    float* __restrict__ out, unsigned short* __restrict__ zws)
{
    const int tid = threadIdx.x;
    const int wv = tid >> 6;
    const int ln = tid & 63;
    const int g = ln >> 4;
    const int c = ln & 15;
    const int rowA = blockIdx.x * 64 + wv * 16 + c;

    float4_ fz = {0.f, 0.f, 0.f, 0.f};
    float4_ acc0 = fz, acc1 = fz, acc2 = fz;
    const float* hrow = h + (size_t)rowA * 512 + g * 8;

    for (int ks = 0; ks < 16; ++ks) {
        float4_ a0 = *(const float4_*)(hrow + ks * 32);
        float4_ a1 = *(const float4_*)(hrow + ks * 32 + 4);
        short8 af;
        af[0] = (short)f2bf(a0[0]); af[1] = (short)f2bf(a0[1]);
        af[2] = (short)f2bf(a0[2]); af[3] = (short)f2bf(a0[3]);
        af[4] = (short)f2bf(a1[0]); af[5] = (short)f2bf(a1[1]);
        af[6] = (short)f2bf(a1[2]); af[7] = (short)f2bf(a1[3]);
        int kbase = ks * 32 + g * 8;
        short8 bf0 = *(const short8*)(wct + (c * 512 + kbase));
        short8 bf1 = *(const short8*)(wct + ((16 + c) * 512 + kbase));
        short8 bf2 = *(const short8*)(wct + ((32 + c) * 512 + kbase));
        acc0 = __builtin_amdgcn_mfma_f32_16x16x32_bf16(af, bf0, acc0, 0, 0, 0);
        acc1 = __builtin_amdgcn_mfma_f32_16x16x32_bf16(af, bf1, acc1, 0, 0, 0);
        acc2 = __builtin_amdgcn_mfma_f32_16x16x32_bf16(af, bf2, acc2, 0, 0, 0);
    }

    const float bm0 = bmu[c], bm1 = bmu[16 + c];
    const float bk0 = bk[0];

    #pragma unroll
    for (int r = 0; r < 4; ++r) {
        const int gm = blockIdx.x * 64 + wv * 16 + 4 * g + r;
        float m0 = acc0[r] + bm0;
        float m1 = acc1[r] + bm1;
        float s = m0 * m0 + m1 * m1;
        s += __shfl_xor(s, 1); s += __shfl_xor(s, 2);
        s += __shfl_xor(s, 4); s += __shfl_xor(s, 8);
        float nrm = fmaxf(sqrtf(s), 1e-12f);
        float mu0 = m0 / nrm, mu1 = m1 / nrm;
        out[(size_t)B_N * 7 + (size_t)gm * 32 + c] = mu0;
        out[(size_t)B_N * 7 + (size_t)gm * 32 + 16 + c] = mu1;

        float kraw = __shfl(acc2[r], g * 16) + bk0;
        float kap = fmaxf(kraw, 0.f) + __logf(1.0f + __expf(-fabsf(kraw))) + 1.0f;
        if (c == 0) out[(size_t)B_N * 39 + gm] = kap;

        float e = __expf(-2.0f * kap);
        float ome = 1.0f - e;
        float w = 0.0f;
        bool done = false;
        #pragma unroll
        for (int t = 0; t < 4; ++t) {
            float zr = zu[t * B_N + gm];
            float ur = uu[t * B_N + gm];
            float zt = zr * ome + e;
            float wt = 1.0f - __logf(zt) / kap;
            bool ac = (__logf(ur) <= 29.0f * __logf(wt) + kap * wt);
            if (ac && !done) w = wt;
            done = done || ac;
        }

        float v0 = v[(size_t)gm * 32 + c];
        float v1 = v[(size_t)gm * 32 + 16 + c];
        float sv = v0 * v0 + v1 * v1;
        sv += __shfl_xor(sv, 1); sv += __shfl_xor(sv, 2);
        sv += __shfl_xor(sv, 4); sv += __shfl_xor(sv, 8);
        float vn = fmaxf(sqrtf(sv), 1e-12f);
        float vn0 = v0 / vn, vn1 = v1 / vn;

        float u0 = vn0 - mu0, u1 = vn1 - mu1;
        float su = u0 * u0 + u1 * u1;
        su += __shfl_xor(su, 1); su += __shfl_xor(su, 2);
        su += __shfl_xor(su, 4); su += __shfl_xor(su, 8);
        float un = fmaxf(sqrtf(su), 1e-12f);
        float uh0 = u0 / un, uh1 = u1 / un;

        float dt = vn0 * uh0 + vn1 * uh1;
        dt += __shfl_xor(dt, 1); dt += __shfl_xor(dt, 2);
        dt += __shfl_xor(dt, 4); dt += __shfl_xor(dt, 8);

        float z0 = (vn0 - 2.0f * dt * uh0) * w;
        float z1 = (vn1 - 2.0f * dt * uh1) * w;
        zws[(size_t)gm * 32 + c] = f2bf(z0);
        zws[(size_t)gm * 32 + 16 + c] = f2bf(z1);
    }
}

// ---------------- mlp: R14 structure, K-loop FULLY unrolled + (512,1) for deep compiler SWP ----------------
// 512 thr (8 waves), BM=64 (rt=4). Wave wv owns N-cols [wv*64, wv*64+64), 4 n-tiles in one pass.
// LDS 67584: x1 [64 rows][1024B] bf16 swizzled; reused as red f32 [8][64][33], then x3f f32 [64][33].
// Full unroll gives the scheduler whole-loop scope to hoist a-fragment loads; (512,1) lifts the
// VGPR cap to 256 (LDS already limits to 1 block/CU, so the declaration costs no occupancy).
__global__ __launch_bounds__(512, 1) void aehr_mlp(
    const unsigned short* __restrict__ zws,
    const unsigned short* __restrict__ w1t,
    const unsigned short* __restrict__ w2k,
    const unsigned short* __restrict__ w3p,
    const float* __restrict__ b1, const float* __restrict__ b2,
    const float* __restrict__ b3, const float* __restrict__ W4,
    const float* __restrict__ b4,
    float* __restrict__ out)
{
    __shared__ __attribute__((aligned(16))) char smem[67584];
    const int tid = threadIdx.x;
    const int wv = tid >> 6;
    const int ln = tid & 63;
    const int g = ln >> 4;
    const int c = ln & 15;
    const int swz = (c & 7) << 4;
    const size_t rowbase = (size_t)blockIdx.x * 64;
    const float4_ fz = {0.f, 0.f, 0.f, 0.f};

    // ---- layer 1: x1 = relu(z @ W1 + b1), swapped mfma -> direct packed LDS store ----
    {
        short8 zf[4];
        #pragma unroll
        for (int rt = 0; rt < 4; ++rt)
            zf[rt] = *(const short8*)(zws + (rowbase + rt * 16 + c) * 32 + g * 8);

        #pragma unroll
        for (int sl = 0; sl < 2; ++sl) {
            const int nb0 = wv * 64 + sl * 32;
            short8 w1f0 = *(const short8*)(w1t + (nb0 + c) * 32 + g * 8);
            short8 w1f1 = *(const short8*)(w1t + (nb0 + 16 + c) * 32 + g * 8);
            float4_ bv0 = *(const float4_*)(b1 + nb0 + 4 * g);
            float4_ bv1 = *(const float4_*)(b1 + nb0 + 16 + 4 * g);
            const int S = wv * 2 + sl;
            #pragma unroll
            for (int rt = 0; rt < 4; ++rt) {
                float4_ d0 = __builtin_amdgcn_mfma_f32_16x16x32_bf16(w1f0, zf[rt], fz, 0, 0, 0);
                float4_ d1 = __builtin_amdgcn_mfma_f32_16x16x32_bf16(w1f1, zf[rt], fz, 0, 0, 0);
                uint4_ u;
                u[0] = pack2bf(fmaxf(d0[0] + bv0[0], 0.f), fmaxf(d0[1] + bv0[1], 0.f));
                u[1] = pack2bf(fmaxf(d0[2] + bv0[2], 0.f), fmaxf(d0[3] + bv0[3], 0.f));
                u[2] = pack2bf(fmaxf(d1[0] + bv1[0], 0.f), fmaxf(d1[1] + bv1[1], 0.f));
                u[3] = pack2bf(fmaxf(d1[2] + bv1[2], 0.f), fmaxf(d1[3] + bv1[3], 0.f));
                const int row = rt * 16 + c;
                *(uint4_*)(smem + row * 1024 + ((S * 64 + g * 16) ^ swz)) = u;
            }
        }
    }
    __syncthreads();

    // ---- layer 2: ONE merged 64-col pass, FULLY unrolled K-loop ----
    float4_ acc[4][4];
    #pragma unroll
    for (int rt = 0; rt < 4; ++rt)
        #pragma unroll
        for (int nt = 0; nt < 4; ++nt) acc[rt][nt] = fz;

    #pragma unroll
    for (int ks = 0; ks < 16; ++ks) {
        const unsigned short* wb = w2k + (size_t)(ks * 4 + g) * 512 * 8 + (wv * 64 + c) * 8;
        short8 a[4];
        #pragma unroll
        for (int nt = 0; nt < 4; ++nt)
            a[nt] = *(const short8*)(wb + nt * 128);
        #pragma unroll
        for (int rt = 0; rt < 4; ++rt) {
            short8 bfr = *(const short8*)(smem + (rt * 16 + c) * 1024 + ((ks * 64 + g * 16) ^ swz));
            #pragma unroll
            for (int nt = 0; nt < 4; ++nt)
                acc[rt][nt] = __builtin_amdgcn_mfma_f32_16x16x32_bf16(a[nt], bfr, acc[rt][nt], 0, 0, 0);
        }
    }

    // ---- layer 3 epilogue: relu+bias, pack into layer-3 B-frags, accumulate x3 ----
    float4_ x3acc[4][2];
    #pragma unroll
    for (int rt = 0; rt < 4; ++rt) { x3acc[rt][0] = fz; x3acc[rt][1] = fz; }
    {
        short8 w3f[2][2];
        #pragma unroll
        for (int S = 0; S < 2; ++S)
            #pragma unroll
            for (int n3 = 0; n3 < 2; ++n3)
                w3f[S][n3] = *(const short8*)(w3p + (n3 * 16 + c) * 512 + (wv * 2 + S) * 32 + g * 8);

        float4_ bv0 = *(const float4_*)(b2 + wv * 64 + 4 * g);
        float4_ bv1 = *(const float4_*)(b2 + wv * 64 + 16 + 4 * g);
        float4_ bv2 = *(const float4_*)(b2 + wv * 64 + 32 + 4 * g);
        float4_ bv3 = *(const float4_*)(b2 + wv * 64 + 48 + 4 * g);

        #pragma unroll
        for (int rt = 0; rt < 4; ++rt) {
            union { uint4_ u; short8 s; } x2a, x2b;
            x2a.u[0] = pack2bf(fmaxf(acc[rt][0][0] + bv0[0], 0.f), fmaxf(acc[rt][0][1] + bv0[1], 0.f));
            x2a.u[1] = pack2bf(fmaxf(acc[rt][0][2] + bv0[2], 0.f), fmaxf(acc[rt][0][3] + bv0[3], 0.f));
            x2a.u[2] = pack2bf(fmaxf(acc[rt][1][0] + bv1[0], 0.f), fmaxf(acc[rt][1][1] + bv1[1], 0.f));
            x2a.u[3] = pack2bf(fmaxf(acc[rt][1][2] + bv1[2], 0.f), fmaxf(acc[rt][1][3] + bv1[3], 0.f));
            x2b.u[0] = pack2bf(fmaxf(acc[rt][2][0] + bv2[0], 0.f), fmaxf(acc[rt][2][1] + bv2[1], 0.f));
            x2b.u[1] = pack2bf(fmaxf(acc[rt][2][2] + bv2[2], 0.f), fmaxf(acc[rt][2][3] + bv2[3], 0.f));
            x2b.u[2] = pack2bf(fmaxf(acc[rt][3][0] + bv3[0], 0.f), fmaxf(acc[rt][3][1] + bv3[1], 0.f));
            x2b.u[3] = pack2bf(fmaxf(acc[rt][3][2] + bv3[2], 0.f), fmaxf(acc[rt][3][3] + bv3[3], 0.f));
            #pragma unroll
            for (int n3 = 0; n3 < 2; ++n3) {
                x3acc[rt][n3] = __builtin_amdgcn_mfma_f32_16x16x32_bf16(w3f[0][n3], x2a.s, x3acc[rt][n3], 0, 0, 0);
                x3acc[rt][n3] = __builtin_amdgcn_mfma_f32_16x16x32_bf16(w3f[1][n3], x2b.s, x3acc[rt][n3], 0, 0, 0);
            }
        }
    }
    __syncthreads();   // all waves done reading x1 -> reuse LDS

    // ---- cross-wave x3 reduce (f32 [8][64][33], exact R7/R8 pattern) ----
    float* red = (float*)smem;
    #pragma unroll
    for (int rt = 0; rt < 4; ++rt)
        #pragma unroll
        for (int t3 = 0; t3 < 2; ++t3)
            #pragma unroll
            for (int r = 0; r < 4; ++r)
                red[wv * 2112 + (rt * 16 + c) * 33 + t3 * 16 + 4 * g + r] = x3acc[rt][t3][r];
    __syncthreads();

    float sums[4];
    #pragma unroll
    for (int k = 0; k < 4; ++k) {
        int idx = tid + k * 512;
        int row = idx >> 5, n = idx & 31;
        float s_ = b3[n];
        #pragma unroll
        for (int w_ = 0; w_ < 8; ++w_) s_ += red[w_ * 2112 + row * 33 + n];
        sums[k] = fmaxf(s_, 0.0f);
    }
    __syncthreads();

    float* x3f = (float*)smem;   // [64][33]
    #pragma unroll
    for (int k = 0; k < 4; ++k) {
        int idx = tid + k * 512;
        x3f[(idx >> 5) * 33 + (idx & 31)] = sums[k];
    }
    __syncthreads();

    // ---- layer 4: 8 threads per row, thread o<7 computes one output ----
    {
        const int row = tid >> 3;      // 0..63
        const int o = tid & 7;
        if (o < 7) {
            const size_t gm = rowbase + row;
            float acc4 = b4[o];
            #pragma unroll
            for (int ci = 0; ci < 32; ++ci)
                acc4 += x3f[row * 33 + ci] * W4[ci * 7 + o];
            out[gm * 7 + o] = acc4;
        }
    }
}

// ---------------- launch ----------------
extern "C" void kernel_launch(void* const* d_in, const int* in_sizes, int n_in,
                              void* d_out, int out_size, void* d_ws, size_t ws_size,
                              hipStream_t stream) {
    const float* h   = (const float*)d_in[0];
    const float* v   = (const float*)d_in[1];
    const float* zu  = (const float*)d_in[2];
    const float* uu  = (const float*)d_in[3];
    const float* Wmu = (const float*)d_in[4];
    const float* bmu = (const float*)d_in[5];
    const float* Wk  = (const float*)d_in[6];
    const float* bk  = (const float*)d_in[7];
    const float* W1  = (const float*)d_in[8];
    const float* b1  = (const float*)d_in[9];
    const float* W2  = (const float*)d_in[10];
    const float* b2  = (const float*)d_in[11];
    const float* W3  = (const float*)d_in[12];
    const float* b3  = (const float*)d_in[13];
    const float* W4  = (const float*)d_in[14];
    const float* b4  = (const float*)d_in[15];

    float* out = (float*)d_out;
    char* ws = (char*)d_ws;
    unsigned short* zws = (unsigned short*)ws;                 // [B][32] bf16
    unsigned short* wct = (unsigned short*)(ws + 8388608);     // [48][512] n-major
    unsigned short* w1t = (unsigned short*)(ws + 8437760);     // [512][32]
    unsigned short* w2k = (unsigned short*)(ws + 8470528);     // [64*512*8] k-major perm
    unsigned short* w3p = (unsigned short*)(ws + 8994816);     // [32][512] perm

    aehr_prep<<<1248, 256, 0, stream>>>(Wmu, Wk, W1, W2, W3, wct, w1t, w2k, w3p);
    aehr_front<<<2048, 256, 0, stream>>>(h, v, zu, uu, bmu, bk, wct, out, zws);
    aehr_mlp<<<2048, 512, 0, stream>>>(zws, w1t, w2k, w3p, b1, b2, b3, W4, b4, out);
}

// Round 19
// 174.758 us; speedup vs baseline: 1.1070x; 1.1070x over previous
//
#include <hip/hip_runtime.h>
#include <stdint.h>

#define B_N 131072

typedef float        float4_ __attribute__((ext_vector_type(4)));
typedef short        short8  __attribute__((ext_vector_type(8)));
typedef unsigned int uint4_  __attribute__((ext_vector_type(4)));

__device__ __forceinline__ unsigned short f2bf(float f) {
    unsigned int u = __float_as_uint(f);
    u += 0x7fffu + ((u >> 16) & 1u);
    return (unsigned short)(u >> 16);
}
__device__ __forceinline__ unsigned int pack2bf(float lo, float hi) {
    return (unsigned int)f2bf(lo) | ((unsigned int)f2bf(hi) << 16);
}

// ---------------- prep: pack bf16 weights into ws (R8/R14-proven) ----------------
// wct [48][512] n-major; w1t [512][32]; w2k k-major sigma-perm; w3p [32][512] sigma-perm
__global__ void aehr_prep(const float* __restrict__ Wmu, const float* __restrict__ Wk,
                          const float* __restrict__ W1, const float* __restrict__ W2,
                          const float* __restrict__ W3,
                          unsigned short* __restrict__ wct, unsigned short* __restrict__ w1t,
                          unsigned short* __restrict__ w2k, unsigned short* __restrict__ w3p) {
    int idx = blockIdx.x * 256 + threadIdx.x;
    if (idx < 48 * 512) {
        int n = idx >> 9, k = idx & 511;
        float v = 0.0f;
        if (n < 32) v = Wmu[k * 32 + n];
        else if (n == 32) v = Wk[k];
        wct[idx] = f2bf(v);
    } else if (idx < 48 * 512 + 512 * 32) {
        int j = idx - 48 * 512;
        int n = j >> 5, k = j & 31;
        w1t[j] = f2bf(W1[k * 512 + n]);
    } else if (idx < 48 * 512 + 512 * 32 + 512 * 512) {
        int j = idx - (48 * 512 + 512 * 32);
        int i = j & 7, t = j >> 3;
        int n = t & 511, gk = t >> 9;      // gk 0..63
        int g = gk & 3, ks = gk >> 2;
        int col = ks * 32 + ((i < 4) ? (4 * g + i) : (16 + 4 * g + (i - 4)));
        w2k[j] = f2bf(W2[col * 512 + n]);
    } else if (idx < 48 * 512 + 512 * 32 + 512 * 512 + 32 * 512) {
        int j = idx - (48 * 512 + 512 * 32 + 512 * 512);
        int n = j >> 9, slot = j & 511;
        int s = slot >> 5, q = slot & 31, g = (q >> 3) & 3, i = q & 7;
        int col = s * 32 + ((i < 4) ? (4 * g + i) : (16 + 4 * g + (i - 4)));
        w3p[j] = f2bf(W3[col * 32 + n]);
    }
}

// ---------------- front: R14 passer (fast transcendentals), byte-identical ----------------
__global__ __launch_bounds__(256, 4) void aehr_front(
    const float* __restrict__ h, const float* __restrict__ v,
    const float* __restrict__ zu, const float* __restrict__ uu,
    const float* __restrict__ bmu, const float* __restrict__ bk,
    const unsigned short* __restrict__ wct,
    float* __restrict__ out, unsigned short* __restrict__ zws)
{
    const int tid = threadIdx.x;
    const int wv = tid >> 6;
    const int ln = tid & 63;
    const int g = ln >> 4;
    const int c = ln & 15;
    const int rowA = blockIdx.x * 64 + wv * 16 + c;

    float4_ fz = {0.f, 0.f, 0.f, 0.f};
    float4_ acc0 = fz, acc1 = fz, acc2 = fz;
    const float* hrow = h + (size_t)rowA * 512 + g * 8;

    for (int ks = 0; ks < 16; ++ks) {
        float4_ a0 = *(const float4_*)(hrow + ks * 32);
        float4_ a1 = *(const float4_*)(hrow + ks * 32 + 4);
        short8 af;
        af[0] = (short)f2bf(a0[0]); af[1] = (short)f2bf(a0[1]);
        af[2] = (short)f2bf(a0[2]); af[3] = (short)f2bf(a0[3]);
        af[4] = (short)f2bf(a1[0]); af[5] = (short)f2bf(a1[1]);
        af[6] = (short)f2bf(a1[2]); af[7] = (short)f2bf(a1[3]);
        int kbase = ks * 32 + g * 8;
        short8 bf0 = *(const short8*)(wct + (c * 512 + kbase));
        short8 bf1 = *(const short8*)(wct + ((16 + c) * 512 + kbase));
        short8 bf2 = *(const short8*)(wct + ((32 + c) * 512 + kbase));
        acc0 = __builtin_amdgcn_mfma_f32_16x16x32_bf16(af, bf0, acc0, 0, 0, 0);
        acc1 = __builtin_amdgcn_mfma_f32_16x16x32_bf16(af, bf1, acc1, 0, 0, 0);
        acc2 = __builtin_amdgcn_mfma_f32_16x16x32_bf16(af, bf2, acc2, 0, 0, 0);
    }

    const float bm0 = bmu[c], bm1 = bmu[16 + c];
    const float bk0 = bk[0];

    #pragma unroll
    for (int r = 0; r < 4; ++r) {
        const int gm = blockIdx.x * 64 + wv * 16 + 4 * g + r;
        float m0 = acc0[r] + bm0;
        float m1 = acc1[r] + bm1;
        float s = m0 * m0 + m1 * m1;
        s += __shfl_xor(s, 1); s += __shfl_xor(s, 2);
        s += __shfl_xor(s, 4); s += __shfl_xor(s, 8);
        float nrm = fmaxf(sqrtf(s), 1e-12f);
        float mu0 = m0 / nrm, mu1 = m1 / nrm;
        out[(size_t)B_N * 7 + (size_t)gm * 32 + c] = mu0;
        out[(size_t)B_N * 7 + (size_t)gm * 32 + 16 + c] = mu1;

        float kraw = __shfl(acc2[r], g * 16) + bk0;
        float kap = fmaxf(kraw, 0.f) + __logf(1.0f + __expf(-fabsf(kraw))) + 1.0f;
        if (c == 0) out[(size_t)B_N * 39 + gm] = kap;

        float e = __expf(-2.0f * kap);
        float ome = 1.0f - e;
        float w = 0.0f;
        bool done = false;
        #pragma unroll
        for (int t = 0; t < 4; ++t) {
            float zr = zu[t * B_N + gm];
            float ur = uu[t * B_N + gm];
            float zt = zr * ome + e;
            float wt = 1.0f - __logf(zt) / kap;
            bool ac = (__logf(ur) <= 29.0f * __logf(wt) + kap * wt);
            if (ac && !done) w = wt;
            done = done || ac;
        }

        float v0 = v[(size_t)gm * 32 + c];
        float v1 = v[(size_t)gm * 32 + 16 + c];
        float sv = v0 * v0 + v1 * v1;
        sv += __shfl_xor(sv, 1); sv += __shfl_xor(sv, 2);
        sv += __shfl_xor(sv, 4); sv += __shfl_xor(sv, 8);
        float vn = fmaxf(sqrtf(sv), 1e-12f);
        float vn0 = v0 / vn, vn1 = v1 / vn;

        float u0 = vn0 - mu0, u1 = vn1 - mu1;
        float su = u0 * u0 + u1 * u1;
        su += __shfl_xor(su, 1); su += __shfl_xor(su, 2);
        su += __shfl_xor(su, 4); su += __shfl_xor(su, 8);
        float un = fmaxf(sqrtf(su), 1e-12f);
        float uh0 = u0 / un, uh1 = u1 / un;

        float dt = vn0 * uh0 + vn1 * uh1;
        dt += __shfl_xor(dt, 1); dt += __shfl_xor(dt, 2);
        dt += __shfl_xor(dt, 4); dt += __shfl_xor(dt, 8);

        float z0 = (vn0 - 2.0f * dt * uh0) * w;
        float z1 = (vn1 - 2.0f * dt * uh1) * w;
        zws[(size_t)gm * 32 + c] = f2bf(z0);
        zws[(size_t)gm * 32 + 16 + c] = f2bf(z1);
    }
}

// ---------------- mlp: merged single N-pass (R8/R14 passer, byte-identical) ----------------
// 512 thr (8 waves), BM=64 (rt=4). Wave wv owns N-cols [wv*64, wv*64+64), all 4 n-tiles in one pass.
// LDS 67584: x1 [64 rows][1024B] bf16 swizzled; reused as red f32 [8][64][33], then x3f f32 [64][33].
__global__ __launch_bounds__(512, 2) void aehr_mlp(
    const unsigned short* __restrict__ zws,
    const unsigned short* __restrict__ w1t,
    const unsigned short* __restrict__ w2k,
    const unsigned short* __restrict__ w3p,
    const float* __restrict__ b1, const float* __restrict__ b2,
    const float* __restrict__ b3, const float* __restrict__ W4,
    const float* __restrict__ b4,
    float* __restrict__ out)
{
    __shared__ __attribute__((aligned(16))) char smem[67584];
    const int tid = threadIdx.x;
    const int wv = tid >> 6;
    const int ln = tid & 63;
    const int g = ln >> 4;
    const int c = ln & 15;
    const int swz = (c & 7) << 4;
    const size_t rowbase = (size_t)blockIdx.x * 64;
    const float4_ fz = {0.f, 0.f, 0.f, 0.f};

    // ---- layer 1: x1 = relu(z @ W1 + b1), swapped mfma -> direct packed LDS store ----
    {
        short8 zf[4];
        #pragma unroll
        for (int rt = 0; rt < 4; ++rt)
            zf[rt] = *(const short8*)(zws + (rowbase + rt * 16 + c) * 32 + g * 8);

        #pragma unroll
        for (int sl = 0; sl < 2; ++sl) {
            const int nb0 = wv * 64 + sl * 32;
            short8 w1f0 = *(const short8*)(w1t + (nb0 + c) * 32 + g * 8);
            short8 w1f1 = *(const short8*)(w1t + (nb0 + 16 + c) * 32 + g * 8);
            float4_ bv0 = *(const float4_*)(b1 + nb0 + 4 * g);
            float4_ bv1 = *(const float4_*)(b1 + nb0 + 16 + 4 * g);
            const int S = wv * 2 + sl;
            #pragma unroll
            for (int rt = 0; rt < 4; ++rt) {
                float4_ d0 = __builtin_amdgcn_mfma_f32_16x16x32_bf16(w1f0, zf[rt], fz, 0, 0, 0);
                float4_ d1 = __builtin_amdgcn_mfma_f32_16x16x32_bf16(w1f1, zf[rt], fz, 0, 0, 0);
                uint4_ u;
                u[0] = pack2bf(fmaxf(d0[0] + bv0[0], 0.f), fmaxf(d0[1] + bv0[1], 0.f));
                u[1] = pack2bf(fmaxf(d0[2] + bv0[2], 0.f), fmaxf(d0[3] + bv0[3], 0.f));
                u[2] = pack2bf(fmaxf(d1[0] + bv1[0], 0.f), fmaxf(d1[1] + bv1[1], 0.f));
                u[3] = pack2bf(fmaxf(d1[2] + bv1[2], 0.f), fmaxf(d1[3] + bv1[3], 0.f));
                const int row = rt * 16 + c;
                *(uint4_*)(smem + row * 1024 + ((S * 64 + g * 16) ^ swz)) = u;
            }
        }
    }
    __syncthreads();

    // ---- layer 2: ONE merged 64-col pass per wave (4 n-tiles x 4 row-tiles) ----
    float4_ acc[4][4];
    #pragma unroll
    for (int rt = 0; rt < 4; ++rt)
        #pragma unroll
        for (int nt = 0; nt < 4; ++nt) acc[rt][nt] = fz;

    #pragma unroll 2
    for (int ks = 0; ks < 16; ++ks) {
        const unsigned short* wb = w2k + (size_t)(ks * 4 + g) * 512 * 8 + (wv * 64 + c) * 8;
        short8 a[4];
        #pragma unroll
        for (int nt = 0; nt < 4; ++nt)
            a[nt] = *(const short8*)(wb + nt * 128);
        #pragma unroll
        for (int rt = 0; rt < 4; ++rt) {
            short8 bfr = *(const short8*)(smem + (rt * 16 + c) * 1024 + ((ks * 64 + g * 16) ^ swz));
            #pragma unroll
            for (int nt = 0; nt < 4; ++nt)
                acc[rt][nt] = __builtin_amdgcn_mfma_f32_16x16x32_bf16(a[nt], bfr, acc[rt][nt], 0, 0, 0);
        }
    }

    // ---- layer 3 epilogue: relu+bias, pack into layer-3 B-frags, accumulate x3 ----
    float4_ x3acc[4][2];
    #pragma unroll
    for (int rt = 0; rt < 4; ++rt) { x3acc[rt][0] = fz; x3acc[rt][1] = fz; }
    {
        short8 w3f[2][2];
        #pragma unroll
        for (int S = 0; S < 2; ++S)
            #pragma unroll
            for (int n3 = 0; n3 < 2; ++n3)
                w3f[S][n3] = *(const short8*)(w3p + (n3 * 16 + c) * 512 + (wv * 2 + S) * 32 + g * 8);

        float4_ bv0 = *(const float4_*)(b2 + wv * 64 + 4 * g);
        float4_ bv1 = *(const float4_*)(b2 + wv * 64 + 16 + 4 * g);
        float4_ bv2 = *(const float4_*)(b2 + wv * 64 + 32 + 4 * g);
        float4_ bv3 = *(const float4_*)(b2 + wv * 64 + 48 + 4 * g);

        #pragma unroll
        for (int rt = 0; rt < 4; ++rt) {
            union { uint4_ u; short8 s; } x2a, x2b;
            x2a.u[0] = pack2bf(fmaxf(acc[rt][0][0] + bv0[0], 0.f), fmaxf(acc[rt][0][1] + bv0[1], 0.f));
            x2a.u[1] = pack2bf(fmaxf(acc[rt][0][2] + bv0[2], 0.f), fmaxf(acc[rt][0][3] + bv0[3], 0.f));
            x2a.u[2] = pack2bf(fmaxf(acc[rt][1][0] + bv1[0], 0.f), fmaxf(acc[rt][1][1] + bv1[1], 0.f));
            x2a.u[3] = pack2bf(fmaxf(acc[rt][1][2] + bv1[2], 0.f), fmaxf(acc[rt][1][3] + bv1[3], 0.f));
            x2b.u[0] = pack2bf(fmaxf(acc[rt][2][0] + bv2[0], 0.f), fmaxf(acc[rt][2][1] + bv2[1], 0.f));
            x2b.u[1] = pack2bf(fmaxf(acc[rt][2][2] + bv2[2], 0.f), fmaxf(acc[rt][2][3] + bv2[3], 0.f));
            x2b.u[2] = pack2bf(fmaxf(acc[rt][3][0] + bv3[0], 0.f), fmaxf(acc[rt][3][1] + bv3[1], 0.f));
            x2b.u[3] = pack2bf(fmaxf(acc[rt][3][2] + bv3[2], 0.f), fmaxf(acc[rt][3][3] + bv3[3], 0.f));
            #pragma unroll
            for (int n3 = 0; n3 < 2; ++n3) {
                x3acc[rt][n3] = __builtin_amdgcn_mfma_f32_16x16x32_bf16(w3f[0][n3], x2a.s, x3acc[rt][n3], 0, 0, 0);
                x3acc[rt][n3] = __builtin_amdgcn_mfma_f32_16x16x32_bf16(w3f[1][n3], x2b.s, x3acc[rt][n3], 0, 0, 0);
            }
        }
    }
    __syncthreads();   // all waves done reading x1 -> reuse LDS

    // ---- cross-wave x3 reduce (f32 [8][64][33], exact R7/R8 pattern) ----
    float* red = (float*)smem;
    #pragma unroll
    for (int rt = 0; rt < 4; ++rt)
        #pragma unroll
        for (int t3 = 0; t3 < 2; ++t3)
            #pragma unroll
            for (int r = 0; r < 4; ++r)
                red[wv * 2112 + (rt * 16 + c) * 33 + t3 * 16 + 4 * g + r] = x3acc[rt][t3][r];
    __syncthreads();

    float sums[4];
    #pragma unroll
    for (int k = 0; k < 4; ++k) {
        int idx = tid + k * 512;
        int row = idx >> 5, n = idx & 31;
        float s_ = b3[n];
        #pragma unroll
        for (int w_ = 0; w_ < 8; ++w_) s_ += red[w_ * 2112 + row * 33 + n];
        sums[k] = fmaxf(s_, 0.0f);
    }
    __syncthreads();

    float* x3f = (float*)smem;   // [64][33]
    #pragma unroll
    for (int k = 0; k < 4; ++k) {
        int idx = tid + k * 512;
        x3f[(idx >> 5) * 33 + (idx & 31)] = sums[k];
    }
    __syncthreads();

    // ---- layer 4: 8 threads per row, thread o<7 computes one output ----
    {
        const int row = tid >> 3;      // 0..63
        const int o = tid & 7;
        if (o < 7) {
            const size_t gm = rowbase + row;
            float acc4 = b4[o];
            #pragma unroll
            for (int ci = 0; ci < 32; ++ci)
                acc4 += x3f[row * 33 + ci] * W4[ci * 7 + o];
            out[gm * 7 + o] = acc4;
        }
    }
}

// ---------------- launch ----------------
extern "C" void kernel_launch(void* const* d_in, const int* in_sizes, int n_in,
                              void* d_out, int out_size, void* d_ws, size_t ws_size,
                              hipStream_t stream) {
    const float* h   = (const float*)d_in[0];
    const float* v   = (const float*)d_in[1];
    const float* zu  = (const float*)d_in[2];
    const float* uu  = (const float*)d_in[3];
    const float* Wmu = (const float*)d_in[4];
    const float* bmu = (const float*)d_in[5];
    const float* Wk  = (const float*)d_in[6];
    const float* bk  = (const float*)d_in[7];
    const float* W1  = (const float*)d_in[8];
    const float* b1  = (const float*)d_in[9];
    const float* W2  = (const float*)d_in[10];
    const float* b2  = (const float*)d_in[11];
    const float* W3  = (const float*)d_in[12];
    const float* b3  = (const float*)d_in[13];
    const float* W4  = (const float*)d_in[14];
    const float* b4  = (const float*)d_in[15];

    float* out = (float*)d_out;
    char* ws = (char*)d_ws;
    unsigned short* zws = (unsigned short*)ws;                 // [B][32] bf16
    unsigned short* wct = (unsigned short*)(ws + 8388608);     // [48][512] n-major
    unsigned short* w1t = (unsigned short*)(ws + 8437760);     // [512][32]
    unsigned short* w2k = (unsigned short*)(ws + 8470528);     // [64*512*8] k-major perm
    unsigned short* w3p = (unsigned short*)(ws + 8994816);     // [32][512] perm

    aehr_prep<<<1248, 256, 0, stream>>>(Wmu, Wk, W1, W2, W3, wct, w1t, w2k, w3p);
    aehr_front<<<2048, 256, 0, stream>>>(h, v, zu, uu, bmu, bk, wct, out, zws);
    aehr_mlp<<<2048, 512, 0, stream>>>(zws, w1t, w2k, w3p, b1, b2, b3, W4, b4, out);
}